// Round 5
// baseline (483.070 us; speedup 1.0000x reference)
//
#include <hip/hip_runtime.h>

// Problem constants (b=4, n=64, d=64, E=4096)
// Single fused kernel: grid = 1024 blocks x 256 thr = 4 blocks/CU on 256 CUs
// (co-resident by construction: __launch_bounds__(256,4), LDS 21.5KB).
// Phases: A pathlin(+nodeproj) | gridbar | B tropical | gridbar | C upath (+node tail)
// ws: zt 4MB | zt2 4MB | a1 64KB | a3 64KB | barrier counters (zeroed per call)

#define GRID 1024u

__device__ __forceinline__ void gridbar(unsigned* c, int t) {
  __syncthreads();
  if (t == 0) {
    __threadfence();  // release: make this block's global writes visible (agent scope)
    __hip_atomic_fetch_add(c, 1u, __ATOMIC_RELEASE, __HIP_MEMORY_SCOPE_AGENT);
    while (__hip_atomic_load(c, __ATOMIC_ACQUIRE, __HIP_MEMORY_SCOPE_AGENT) < GRID) {
      __builtin_amdgcn_s_sleep(2);
    }
  }
  __syncthreads();
  __threadfence();    // acquire: invalidate stale L1/L2 before reading others' data
}

__global__ __launch_bounds__(256, 4) void k_fused(
    const float* __restrict__ ne, const float* __restrict__ pe,
    const int* __restrict__ eidx,
    const float* __restrict__ Whz, const float* __restrict__ bhz,
    const float* __restrict__ Wzz, const float* __restrict__ bzz,
    const float* __restrict__ Wnm, const float* __restrict__ bnm,
    float* __restrict__ zt, float* __restrict__ zt2,
    float* __restrict__ a1, float* __restrict__ a3,
    float* __restrict__ out0, float* __restrict__ out1,
    unsigned* __restrict__ bar) {
  int t = threadIdx.x, lane = t & 63, g = t >> 6;
  int blk = blockIdx.x;
  __shared__ float sROW[1024];   // 4KB broadcast staging (per phase)
  __shared__ int   elist[4096];  // 16KB node tail
  __shared__ float part[4][64];
  __shared__ float nlal[2][64];

  // ========== Phase A: z = pe @ Whz + bhz, transposed store ==========
  {
    int bi = blk >> 2, q = blk & 3;       // bi = b*64+i, q = k-quarter
    int b = bi >> 6, i = bi & 63;
    // stage pe rows [q*16, q*16+16) of row-block bi (4KB contiguous, coalesced)
    ((float4*)sROW)[t] = ((const float4*)(pe + (size_t)bi * 4096 + q * 1024))[t];
    // Whz column in VGPRs: wreg[c] = Whz[c][lane]  (coalesced, L2-hot)
    float wreg[64];
#pragma unroll
    for (int c = 0; c < 64; ++c) wreg[c] = Whz[c * 64 + lane];
    __syncthreads();
    float bv = bhz[lane];
    float acc[4] = {bv, bv, bv, bv};
    int kl0 = g * 4;
#pragma unroll
    for (int c = 0; c < 64; c += 4) {
#pragma unroll
      for (int kk = 0; kk < 4; ++kk) {
        const float4 p = *(const float4*)&sROW[(kl0 + kk) * 64 + c];  // broadcast b128
        acc[kk] += p.x * wreg[c] + p.y * wreg[c + 1]
                 + p.z * wreg[c + 2] + p.w * wreg[c + 3];
      }
    }
    // transposed store: d = lane, 4 consecutive k -> one float4
    float* dst = zt + (size_t)b * 262144 + (size_t)lane * 4096
               + (size_t)i * 64 + q * 16 + kl0;
    *(float4*)dst = make_float4(acc[0], acc[1], acc[2], acc[3]);
    // nodeproj a1/a3 (row r = blk) for blocks 0..255; waves 0,1 only
    if (blk < 256) {
      const float* nr = ne + blk * 64;
      if (g == 0) {
        float s1 = 0.f;
        for (int d2 = 0; d2 < 64; ++d2) s1 += nr[d2] * Wzz[d2 * 64 + lane];
        a1[blk * 64 + lane] = s1;
      } else if (g == 1) {
        float s3 = 0.f;
        for (int d2 = 0; d2 < 64; ++d2) s3 += nr[d2] * Wzz[(128 + d2) * 64 + lane];
        a3[blk * 64 + lane] = s3;
      }
    }
  }
  gridbar(bar + 0, t);

  // ========== Phase B: tropical max-plus square per (b,d) slice ==========
  {
    int slice = blk >> 2, iq = blk & 3;   // slice = b*64+d
    const float* Ag = zt + (size_t)slice * 4096;
    // stage rows [iq*16, iq*16+16) (4KB contiguous, coalesced)
    ((float4*)sROW)[t] = ((const float4*)(Ag + iq * 1024))[t];
    // column M[k][lane] in VGPRs (coalesced 256B loads)
    float colreg[64];
#pragma unroll
    for (int k = 0; k < 64; ++k) colreg[k] = Ag[k * 64 + lane];
    __syncthreads();
    int lr0 = g * 4, i0 = iq * 16 + lr0;
    float acc[4];
#pragma unroll
    for (int ii = 0; ii < 4; ++ii) acc[ii] = Ag[(i0 + ii) * 64 + lane];  // max(zc, z)
#pragma unroll
    for (int k = 0; k < 64; k += 4) {
#pragma unroll
      for (int ii = 0; ii < 4; ++ii) {
        const float4 a = *(const float4*)&sROW[(lr0 + ii) * 64 + k];  // broadcast b128
        float m0 = fmaxf(a.x + colreg[k], a.y + colreg[k + 1]);
        float m1 = fmaxf(a.z + colreg[k + 2], a.w + colreg[k + 3]);
        acc[ii] = fmaxf(acc[ii], fmaxf(m0, m1));
      }
    }
    float* Og = zt2 + (size_t)slice * 4096 + (size_t)i0 * 64;
#pragma unroll
    for (int ii = 0; ii < 4; ++ii) Og[ii * 64 + lane] = acc[ii];
  }
  gridbar(bar + 16, t);

  // ========== Phase C: u_path = relu(a1 + z2@W2 + a3 + bzz) + pe ==========
  {
    int bi = blk >> 2, jq = blk & 3;
    int b = bi >> 6, i = bi & 63;
    // W2 column in VGPRs: w2[d] = Wzz[64+d][lane]
    float w2[64];
#pragma unroll
    for (int d = 0; d < 64; ++d) w2[d] = Wzz[(64 + d) * 64 + lane];
    // stage sZ[d][jl] (64 d x 16 j = 4KB)
    {
      int d2 = t >> 2, c4 = t & 3;
      const float* src = zt2 + (size_t)b * 262144 + (size_t)d2 * 4096
                       + (size_t)i * 64 + jq * 16 + c4 * 4;
      *(float4*)&sROW[d2 * 16 + c4 * 4] = *(const float4*)src;
    }
    __syncthreads();
    int j0 = jq * 16 + g * 4;
    float base = a1[bi * 64 + lane] + bzz[lane];
    float acc[4] = {base, base, base, base};
#pragma unroll
    for (int d = 0; d < 64; ++d) {
      const float4 z4 = *(const float4*)&sROW[d * 16 + g * 4];  // broadcast b128
      acc[0] += z4.x * w2[d];
      acc[1] += z4.y * w2[d];
      acc[2] += z4.z * w2[d];
      acc[3] += z4.w * w2[d];
    }
    const float* a3b = a3 + (size_t)b * 4096;
    size_t ob = (size_t)bi * 4096 + (size_t)j0 * 64;
#pragma unroll
    for (int jj = 0; jj < 4; ++jj) {
      float v = acc[jj] + a3b[(j0 + jj) * 64 + lane];
      v = fmaxf(v, 0.f);
      out1[ob + jj * 64 + lane] = v + pe[ob + jj * 64 + lane];
    }
  }

  // ========== Node MLP tail: blocks 0..255, row r = blk ==========
  if (blk < 256) {
    int r = blk;
    const int* srcv = eidx;
    const int* dstv = eidx + 4096;
    int cntw = 0;
    unsigned long long ltmask = (lane == 63) ? 0x7fffffffffffffffull
                                             : ((1ull << lane) - 1ull);
    for (int q = 0; q < 16; ++q) {
      int e2 = g * 1024 + q * 64 + lane;
      bool match = (dstv[e2] == r);
      unsigned long long mask = __ballot(match);
      if (match) {
        int pos = cntw + __popcll(mask & ltmask);
        elist[g * 1024 + pos] = srcv[e2];
      }
      cntw += __popcll(mask);
    }
    float accA = 0.f;
    for (int m = 0; m < cntw; ++m) accA += ne[elist[g * 1024 + m] * 64 + lane];
    part[g][lane] = accA;
    if (g == 0) nlal[0][lane] = ne[r * 64 + lane];
    __syncthreads();
    if (g == 0)
      nlal[1][lane] = part[0][lane] + part[1][lane] + part[2][lane] + part[3][lane];
    __syncthreads();
    float s = 0.f;
    for (int d2 = g * 16; d2 < g * 16 + 16; ++d2) {
      s += nlal[0][d2] * Wnm[d2 * 64 + lane]
         + nlal[1][d2] * Wnm[(64 + d2) * 64 + lane];
    }
    part[g][lane] = s;
    __syncthreads();
    if (g == 0) {
      float v = part[0][lane] + part[1][lane] + part[2][lane] + part[3][lane]
                + bnm[lane];
      v = fmaxf(v, 0.f);
      out0[r * 64 + lane] = v + nlal[0][lane];
    }
  }
}

extern "C" void kernel_launch(void* const* d_in, const int* in_sizes, int n_in,
                              void* d_out, int out_size, void* d_ws, size_t ws_size,
                              hipStream_t stream) {
  const float* node = (const float*)d_in[0];
  const float* pe   = (const float*)d_in[1];
  const int*   eidx = (const int*)d_in[2];
  const float* Whz  = (const float*)d_in[3];
  const float* bhz  = (const float*)d_in[4];
  const float* Wzz  = (const float*)d_in[5];
  const float* bzz  = (const float*)d_in[6];
  const float* Wnm  = (const float*)d_in[7];
  const float* bnm  = (const float*)d_in[8];
  float* out0 = (float*)d_out;
  float* out1 = out0 + 16384;
  float* zt  = (float*)d_ws;                 // 4 MB
  float* zt2 = zt + 1048576;                 // 4 MB
  float* a1  = zt2 + 1048576;                // 64 KB
  float* a3  = a1 + 16384;                   // 64 KB
  unsigned* bar = (unsigned*)(a3 + 16384);   // 2 counters, 64B apart

  hipMemsetAsync(bar, 0, 128, stream);       // graph-capturable; per-call reset
  hipLaunchKernelGGL(k_fused, dim3(GRID), dim3(256), 0, stream,
                     node, pe, eidx, Whz, bhz, Wzz, bzz, Wnm, bnm,
                     zt, zt2, a1, a3, out0, out1, bar);
}

// Round 6
// 40.024 us; speedup vs baseline: 12.0696x; 12.0696x over previous
//
#include <hip/hip_runtime.h>

// Problem constants (b=4, n=64, d=64, E=4096)
// zt  layout: [b][d][i][k] -> ((b*64+d)*64+i)*64+k   (4 MB)
// zt2: tropical output, same layout (4 MB)
// a1[r][e], a3[r][e] : r = b*64+i (node row), 64 KB each
//
// Geometry: 128-thread blocks (2 waves), 8 blocks/CU -> 16 waves/CU.
// Broadcast operand: LDS b128 wave-uniform reads. Per-lane operand: VGPR
// columns from coalesced global loads (L2-hot).

// K1: z = pe@Whz + b, transposed store. grid = 2048: (bi, k-eighth)
__global__ __launch_bounds__(128) void k_pathlin(
    const float* __restrict__ pe, const float* __restrict__ Whz,
    const float* __restrict__ bhz, float* __restrict__ zt) {
  int blk = blockIdx.x;
  int bi = blk >> 3, q = blk & 7;         // bi = b*64+i, q = k-eighth
  int b = bi >> 6, i = bi & 63;
  int t = threadIdx.x, lane = t & 63, g = t >> 6;
  __shared__ float sROW[512];             // 8 pe rows (2KB)
  ((float4*)sROW)[t] = ((const float4*)(pe + (size_t)bi * 4096 + q * 512))[t];
  // Whz column in VGPRs: wreg[c] = Whz[c][lane]  (coalesced, L2-hot)
  float wreg[64];
#pragma unroll
  for (int c = 0; c < 64; ++c) wreg[c] = Whz[c * 64 + lane];
  float bv = bhz[lane];
  __syncthreads();
  float acc[4] = {bv, bv, bv, bv};
  int kl0 = g * 4;                        // local row within the 8 staged
#pragma unroll
  for (int c = 0; c < 64; c += 4) {
#pragma unroll
    for (int kk = 0; kk < 4; ++kk) {
      const float4 p = *(const float4*)&sROW[(kl0 + kk) * 64 + c];  // broadcast b128
      acc[kk] += p.x * wreg[c] + p.y * wreg[c + 1]
               + p.z * wreg[c + 2] + p.w * wreg[c + 3];
    }
  }
  // transposed store: d = lane, 4 consecutive k -> one float4
  float* dst = zt + (size_t)b * 262144 + (size_t)lane * 4096
             + (size_t)i * 64 + q * 8 + kl0;
  *(float4*)dst = make_float4(acc[0], acc[1], acc[2], acc[3]);
}

// K2: blocks [0,2048): tropical eighth-slices; [2048,2304): node MLP + nodeproj
__global__ __launch_bounds__(128) void k_trop_node(
    const float* __restrict__ zt, float* __restrict__ zt2,
    const float* __restrict__ ne, const int* __restrict__ eidx,
    const float* __restrict__ Wzz, const float* __restrict__ Wnm,
    const float* __restrict__ bnm,
    float* __restrict__ a1, float* __restrict__ a3, float* __restrict__ out0) {
  int t = threadIdx.x, lane = t & 63, g = t >> 6;
  __shared__ int elist[4096];             // 16KB (node branch); aliases sROW
  float* sROW = (float*)elist;            // 8 rows (2KB) for tropical branch
  __shared__ float part[2][64];
  __shared__ float nlal[2][64];
  if (blockIdx.x < 2048) {
    int slice = blockIdx.x >> 3, iq = blockIdx.x & 7;   // slice = b*64+d
    const float* Ag = zt + (size_t)slice * 4096;
    // stage rows [iq*8, iq*8+8) (2KB, coalesced)
    ((float4*)sROW)[t] = ((const float4*)(Ag + iq * 512))[t];
    // column A[k][lane] in VGPRs (coalesced 256B loads, L2-hot)
    float colreg[64];
#pragma unroll
    for (int k = 0; k < 64; ++k) colreg[k] = Ag[k * 64 + lane];
    __syncthreads();
    int lr0 = g * 4, i0 = iq * 8 + lr0;
    float acc[4];
#pragma unroll
    for (int ii = 0; ii < 4; ++ii) acc[ii] = sROW[(lr0 + ii) * 64 + lane];  // max(zc,z)
#pragma unroll
    for (int k = 0; k < 64; k += 4) {
#pragma unroll
      for (int ii = 0; ii < 4; ++ii) {
        const float4 a = *(const float4*)&sROW[(lr0 + ii) * 64 + k];  // broadcast b128
        float m0 = fmaxf(a.x + colreg[k], a.y + colreg[k + 1]);
        float m1 = fmaxf(a.z + colreg[k + 2], a.w + colreg[k + 3]);
        acc[ii] = fmaxf(acc[ii], fmaxf(m0, m1));
      }
    }
    float* Og = zt2 + (size_t)slice * 4096 + (size_t)i0 * 64;
#pragma unroll
    for (int ii = 0; ii < 4; ++ii) Og[ii * 64 + lane] = acc[ii];
  } else {
    int r = blockIdx.x - 2048;
    const int* srcv = eidx;
    const int* dstv = eidx + 4096;
    // wave g scans edges [g*2048, (g+1)*2048) with ballot compaction
    int cntw = 0;
    unsigned long long ltmask = (lane == 63) ? 0x7fffffffffffffffull
                                             : ((1ull << lane) - 1ull);
    for (int q = 0; q < 32; ++q) {
      int e2 = g * 2048 + q * 64 + lane;
      bool match = (dstv[e2] == r);
      unsigned long long mask = __ballot(match);
      if (match) {
        int pos = cntw + __popcll(mask & ltmask);
        elist[g * 2048 + pos] = srcv[e2];
      }
      cntw += __popcll(mask);
    }
    float accA = 0.f;
    for (int m = 0; m < cntw; ++m) accA += ne[elist[g * 2048 + m] * 64 + lane];
    part[g][lane] = accA;
    if (g == 0) nlal[0][lane] = ne[r * 64 + lane];
    __syncthreads();
    if (g == 0) nlal[1][lane] = part[0][lane] + part[1][lane];
    __syncthreads();
    // u_node partials: wave g handles d2 in [g*32, g*32+32)
    float s = 0.f;
    for (int d2 = g * 32; d2 < g * 32 + 32; ++d2) {
      s += nlal[0][d2] * Wnm[d2 * 64 + lane]
         + nlal[1][d2] * Wnm[(64 + d2) * 64 + lane];
    }
    part[g][lane] = s;
    // nodeproj for row r
    const float* nr = ne + r * 64;
    if (g == 0) {
      float s1 = 0.f;
      for (int d2 = 0; d2 < 64; ++d2) s1 += nr[d2] * Wzz[d2 * 64 + lane];
      a1[r * 64 + lane] = s1;
    } else {
      float s3 = 0.f;
      for (int d2 = 0; d2 < 64; ++d2) s3 += nr[d2] * Wzz[(128 + d2) * 64 + lane];
      a3[r * 64 + lane] = s3;
    }
    __syncthreads();
    if (g == 0) {
      float v = part[0][lane] + part[1][lane] + bnm[lane];
      v = fmaxf(v, 0.f);
      out0[r * 64 + lane] = v + nlal[0][lane];
    }
  }
}

// K3: u_path. grid = 2048: (bi, j-eighth)
__global__ __launch_bounds__(128) void k_upath(
    const float* __restrict__ zt2, const float* __restrict__ Wzz,
    const float* __restrict__ bzz, const float* __restrict__ a1,
    const float* __restrict__ a3, const float* __restrict__ pe,
    float* __restrict__ out1) {
  int blk = blockIdx.x;
  int bi = blk >> 3, j8 = blk & 7;
  int b = bi >> 6, i = bi & 63;
  int t = threadIdx.x, lane = t & 63, g = t >> 6;
  __shared__ float sZ[512];               // [d][8 j] (2KB)
  {
    int d2 = t >> 1, jo = (t & 1) * 4;
    const float* src = zt2 + (size_t)b * 262144 + (size_t)d2 * 4096
                     + (size_t)i * 64 + j8 * 8 + jo;
    *(float4*)&sZ[d2 * 8 + jo] = *(const float4*)src;
  }
  // W2 column in VGPRs: w2[d] = Wzz[64+d][lane]  (coalesced, L2-hot)
  float w2[64];
#pragma unroll
  for (int d = 0; d < 64; ++d) w2[d] = Wzz[(64 + d) * 64 + lane];
  float base = a1[bi * 64 + lane] + bzz[lane];
  __syncthreads();
  float acc[4] = {base, base, base, base};
#pragma unroll
  for (int d = 0; d < 64; ++d) {
    const float4 z4 = *(const float4*)&sZ[d * 8 + g * 4];   // broadcast b128
    acc[0] += z4.x * w2[d];
    acc[1] += z4.y * w2[d];
    acc[2] += z4.z * w2[d];
    acc[3] += z4.w * w2[d];
  }
  int j0 = j8 * 8 + g * 4;
  const float* a3b = a3 + (size_t)b * 4096;
  size_t ob = (size_t)bi * 4096 + (size_t)j0 * 64;
#pragma unroll
  for (int jj = 0; jj < 4; ++jj) {
    float v = acc[jj] + a3b[(j0 + jj) * 64 + lane];
    v = fmaxf(v, 0.f);
    out1[ob + jj * 64 + lane] = v + pe[ob + jj * 64 + lane];
  }
}

extern "C" void kernel_launch(void* const* d_in, const int* in_sizes, int n_in,
                              void* d_out, int out_size, void* d_ws, size_t ws_size,
                              hipStream_t stream) {
  const float* node = (const float*)d_in[0];
  const float* pe   = (const float*)d_in[1];
  const int*   eidx = (const int*)d_in[2];
  const float* Whz  = (const float*)d_in[3];
  const float* bhz  = (const float*)d_in[4];
  const float* Wzz  = (const float*)d_in[5];
  const float* bzz  = (const float*)d_in[6];
  const float* Wnm  = (const float*)d_in[7];
  const float* bnm  = (const float*)d_in[8];
  float* out0 = (float*)d_out;
  float* out1 = out0 + 16384;
  float* zt  = (float*)d_ws;                // 4 MB
  float* zt2 = zt + 1048576;                // 4 MB
  float* a1  = zt2 + 1048576;               // 64 KB
  float* a3  = a1 + 16384;                  // 64 KB

  hipLaunchKernelGGL(k_pathlin, dim3(2048), dim3(128), 0, stream, pe, Whz, bhz, zt);
  hipLaunchKernelGGL(k_trop_node, dim3(2304), dim3(128), 0, stream,
                     zt, zt2, node, eidx, Wzz, Wnm, bnm, a1, a3, out0);
  hipLaunchKernelGGL(k_upath, dim3(2048), dim3(128), 0, stream,
                     zt2, Wzz, bzz, a1, a3, pe, out1);
}

// Round 7
// 34.179 us; speedup vs baseline: 14.1335x; 1.1710x over previous
//
#include <hip/hip_runtime.h>

// Problem constants (b=4, n=64, d=64, E=4096)
// zt  layout: [b][d][i][k] -> ((b*64+d)*64+i)*64+k   (4 MB)
// zt2: tropical output, same layout (4 MB)
// a1[r][e], a3[r][e] : r = b*64+i (node row), 64 KB each
//
// Mechanism: broadcast operand lives in VGPRs with lane = broadcast index;
// inner loops use v_readlane (compile-time lane idx) -> pure VALU, zero DS.
// Per-lane operand is a 64-deep VGPR column from coalesced global loads.

__device__ __forceinline__ float rdl(float v, int l) {
  return __uint_as_float(__builtin_amdgcn_readlane(__float_as_uint(v), l));
}

// K1: z = pe@Whz + bhz, transposed store. grid = 1024: (bi, k-quarter)
__global__ __launch_bounds__(256) void k_pathlin(
    const float* __restrict__ pe, const float* __restrict__ Whz,
    const float* __restrict__ bhz, float* __restrict__ zt) {
  int blk = blockIdx.x;
  int bi = blk >> 2, q = blk & 3;         // bi = b*64+i
  int b = bi >> 6, i = bi & 63;
  int t = threadIdx.x, lane = t & 63, g = t >> 6;
  int k0 = q * 16 + g * 4;                // this wave's 4 k-rows
  // per-lane W column: wreg[c] = Whz[c][d=lane]  (coalesced, L2-hot)
  float wreg[64];
#pragma unroll
  for (int c = 0; c < 64; ++c) wreg[c] = Whz[c * 64 + lane];
  // broadcast source rows: preg[r][lane] = pe[bi][k0+r][c=lane] (coalesced)
  const float* peb = pe + (size_t)bi * 4096 + (size_t)k0 * 64;
  float p0 = peb[lane], p1 = peb[64 + lane], p2 = peb[128 + lane], p3 = peb[192 + lane];
  float bv = bhz[lane];
  float a0 = bv, a1v = bv, a2 = bv, a3v = bv;
#pragma unroll
  for (int c = 0; c < 64; ++c) {
    float w = wreg[c];
    a0  += rdl(p0, c) * w;
    a1v += rdl(p1, c) * w;
    a2  += rdl(p2, c) * w;
    a3v += rdl(p3, c) * w;
  }
  // transposed store: d = lane, 4 consecutive k -> one float4 (scattered lines, L2-absorbed)
  float* dst = zt + (size_t)b * 262144 + (size_t)lane * 4096 + (size_t)i * 64 + k0;
  *(float4*)dst = make_float4(a0, a1v, a2, a3v);
}

// K2: blocks [0,1024): tropical; [1024,1280): node MLP + nodeproj
__global__ __launch_bounds__(256) void k_trop_node(
    const float* __restrict__ zt, float* __restrict__ zt2,
    const float* __restrict__ ne, const int* __restrict__ eidx,
    const float* __restrict__ Wzz, const float* __restrict__ Wnm,
    const float* __restrict__ bnm,
    float* __restrict__ a1, float* __restrict__ a3, float* __restrict__ out0) {
  int t = threadIdx.x, lane = t & 63, g = t >> 6;
  __shared__ int elist[4096];             // node branch only
  __shared__ float part[4][64];
  __shared__ float nlal[2][64];
  if (blockIdx.x < 1024) {
    int slice = blockIdx.x >> 2, iq = blockIdx.x & 3;   // slice = b*64+d
    const float* Ag = zt + (size_t)slice * 4096;
    // per-lane column: colreg[k] = A[k][j=lane]  (coalesced)
    float colreg[64];
#pragma unroll
    for (int k = 0; k < 64; ++k) colreg[k] = Ag[k * 64 + lane];
    int i0 = iq * 16 + g * 4;             // this wave's 4 output rows
    // broadcast source rows (and init, = z term): preg[r][lane] = A[i0+r][lane]
    const float* rb = Ag + (size_t)i0 * 64;
    float p0 = rb[lane], p1 = rb[64 + lane], p2 = rb[128 + lane], p3 = rb[192 + lane];
    float c0 = p0, c1 = p1, c2 = p2, c3 = p3;   // acc init = max(z_conv, z)
#pragma unroll
    for (int k = 0; k < 64; ++k) {
      float ck = colreg[k];
      c0 = fmaxf(c0, rdl(p0, k) + ck);
      c1 = fmaxf(c1, rdl(p1, k) + ck);
      c2 = fmaxf(c2, rdl(p2, k) + ck);
      c3 = fmaxf(c3, rdl(p3, k) + ck);
    }
    float* Og = zt2 + (size_t)slice * 4096 + (size_t)i0 * 64;
    Og[lane] = c0;
    Og[64 + lane] = c1;
    Og[128 + lane] = c2;
    Og[192 + lane] = c3;
  } else {
    int r = blockIdx.x - 1024;
    const int* srcv = eidx;
    const int* dstv = eidx + 4096;
    int cntw = 0;
    unsigned long long ltmask = (lane == 63) ? 0x7fffffffffffffffull
                                             : ((1ull << lane) - 1ull);
    for (int q = 0; q < 16; ++q) {
      int e2 = g * 1024 + q * 64 + lane;
      bool match = (dstv[e2] == r);
      unsigned long long mask = __ballot(match);
      if (match) {
        int pos = cntw + __popcll(mask & ltmask);
        elist[g * 1024 + pos] = srcv[e2];
      }
      cntw += __popcll(mask);
    }
    float accA = 0.f;
    for (int m = 0; m < cntw; ++m) accA += ne[elist[g * 1024 + m] * 64 + lane];
    part[g][lane] = accA;
    if (g == 0) nlal[0][lane] = ne[r * 64 + lane];
    __syncthreads();
    if (g == 0)
      nlal[1][lane] = part[0][lane] + part[1][lane] + part[2][lane] + part[3][lane];
    __syncthreads();
    float s = 0.f;
    for (int d2 = g * 16; d2 < g * 16 + 16; ++d2) {
      s += nlal[0][d2] * Wnm[d2 * 64 + lane]
         + nlal[1][d2] * Wnm[(64 + d2) * 64 + lane];
    }
    part[g][lane] = s;
    if (g == 0) {
      const float* nr = ne + r * 64;
      float s1 = 0.f;
      for (int d2 = 0; d2 < 64; ++d2) s1 += nr[d2] * Wzz[d2 * 64 + lane];
      a1[r * 64 + lane] = s1;
    } else if (g == 1) {
      const float* nr = ne + r * 64;
      float s3 = 0.f;
      for (int d2 = 0; d2 < 64; ++d2) s3 += nr[d2] * Wzz[(128 + d2) * 64 + lane];
      a3[r * 64 + lane] = s3;
    }
    __syncthreads();
    if (g == 0) {
      float v = part[0][lane] + part[1][lane] + part[2][lane] + part[3][lane]
                + bnm[lane];
      v = fmaxf(v, 0.f);
      out0[r * 64 + lane] = v + nlal[0][lane];
    }
  }
}

// K3: u_path. grid = 1024: (bi, j-quarter); wave handles 4 consecutive j.
__global__ __launch_bounds__(256) void k_upath(
    const float* __restrict__ zt2, const float* __restrict__ Wzz,
    const float* __restrict__ bzz, const float* __restrict__ a1,
    const float* __restrict__ a3, const float* __restrict__ pe,
    float* __restrict__ out1) {
  int blk = blockIdx.x;
  int bi = blk >> 2, jq = blk & 3;
  int b = bi >> 6, i = bi & 63;
  int t = threadIdx.x, lane = t & 63, g = t >> 6;
  int j0 = jq * 16 + g * 4;
  // per-lane W2 column: wreg[d] = Wzz[64+d][e=lane]  (coalesced, L2-hot)
  float wreg[64];
#pragma unroll
  for (int d = 0; d < 64; ++d) wreg[d] = Wzz[(64 + d) * 64 + lane];
  // broadcast source: one scattered float4 gather; lane d holds z2[b][d][i][j0..j0+3]
  const float4 zq = *(const float4*)(zt2 + (size_t)b * 262144
                    + (size_t)lane * 4096 + (size_t)i * 64 + j0);
  float base = a1[bi * 64 + lane] + bzz[lane];
  float a0 = base, a1v = base, a2 = base, a3v = base;
#pragma unroll
  for (int d = 0; d < 64; ++d) {
    float w = wreg[d];
    a0  += rdl(zq.x, d) * w;
    a1v += rdl(zq.y, d) * w;
    a2  += rdl(zq.z, d) * w;
    a3v += rdl(zq.w, d) * w;
  }
  const float* a3b = a3 + (size_t)b * 4096;
  size_t ob = (size_t)bi * 4096 + (size_t)j0 * 64;
  float acc[4] = {a0, a1v, a2, a3v};
#pragma unroll
  for (int jj = 0; jj < 4; ++jj) {
    float v = acc[jj] + a3b[(j0 + jj) * 64 + lane];
    v = fmaxf(v, 0.f);
    out1[ob + jj * 64 + lane] = v + pe[ob + jj * 64 + lane];
  }
}

extern "C" void kernel_launch(void* const* d_in, const int* in_sizes, int n_in,
                              void* d_out, int out_size, void* d_ws, size_t ws_size,
                              hipStream_t stream) {
  const float* node = (const float*)d_in[0];
  const float* pe   = (const float*)d_in[1];
  const int*   eidx = (const int*)d_in[2];
  const float* Whz  = (const float*)d_in[3];
  const float* bhz  = (const float*)d_in[4];
  const float* Wzz  = (const float*)d_in[5];
  const float* bzz  = (const float*)d_in[6];
  const float* Wnm  = (const float*)d_in[7];
  const float* bnm  = (const float*)d_in[8];
  float* out0 = (float*)d_out;
  float* out1 = out0 + 16384;
  float* zt  = (float*)d_ws;                // 4 MB
  float* zt2 = zt + 1048576;                // 4 MB
  float* a1  = zt2 + 1048576;               // 64 KB
  float* a3  = a1 + 16384;                  // 64 KB

  hipLaunchKernelGGL(k_pathlin, dim3(1024), dim3(256), 0, stream, pe, Whz, bhz, zt);
  hipLaunchKernelGGL(k_trop_node, dim3(1280), dim3(256), 0, stream,
                     zt, zt2, node, eidx, Wzz, Wnm, bnm, a1, a3, out0);
  hipLaunchKernelGGL(k_upath, dim3(1024), dim3(256), 0, stream,
                     zt2, Wzz, bzz, a1, a3, pe, out1);
}

// Round 9
// 27.314 us; speedup vs baseline: 17.6857x; 1.2513x over previous
//
#include <hip/hip_runtime.h>

// Problem constants (b=4, n=64, d=64, E=4096)
// zt  layout: [b][d][i][k] -> ((b*64+d)*64+i)*64+k   (4 MB)
// zt2: tropical output, same layout (4 MB)
// a1[r][e], a3[r][e] : r = b*64+i (node row), 64 KB each
//
// Geometry: 256 blocks x 1024 threads (16 waves). Each 16KB tile staged ONCE
// per block and shared by all 16 waves. Broadcast operand: LDS b128
// wave-uniform reads; per-lane operand: LDS b32 (conflict-free).

// K1: z = pe@Whz + bhz (transposed store) + node MLP + nodeproj. grid = 256 (bi)
__global__ __launch_bounds__(1024) void k_pathlin_node(
    const float* __restrict__ ne, const float* __restrict__ pe,
    const int* __restrict__ eidx,
    const float* __restrict__ Whz, const float* __restrict__ bhz,
    const float* __restrict__ Wzz,
    const float* __restrict__ Wnm, const float* __restrict__ bnm,
    float* __restrict__ zt, float* __restrict__ a1, float* __restrict__ a3,
    float* __restrict__ out0) {
  int bi = blockIdx.x;                    // b*64 + i == node row
  int b = bi >> 6, i = bi & 63;
  int t = threadIdx.x, lane = t & 63, w = t >> 6;   // 16 waves
  __shared__ float sP[4096];              // pe tile [k][c], 16KB (single array!)
  __shared__ float sW[4096];              // Whz [c][d], 16KB
  __shared__ float part[16][64];
  __shared__ float nl[64], al[64];
  // stage pe row-block (16KB) and Whz (16KB): 1 float4 per thread each
  ((float4*)sP)[t] = ((const float4*)(pe + (size_t)bi * 4096))[t];
  ((float4*)sW)[t] = ((const float4*)Whz)[t];
  float bv = bhz[lane];
  if (w == 0) nl[lane] = ne[bi * 64 + lane];
  __syncthreads();
  // compute: lane = d, wave w owns k in [w*4, w*4+4)
  float acc[4] = {bv, bv, bv, bv};
  int k0 = w * 4;
#pragma unroll
  for (int c = 0; c < 64; c += 4) {
    float w0 = sW[(c + 0) * 64 + lane], w1 = sW[(c + 1) * 64 + lane];
    float w2 = sW[(c + 2) * 64 + lane], w3 = sW[(c + 3) * 64 + lane];
#pragma unroll
    for (int kk = 0; kk < 4; ++kk) {
      const float4 p = *(const float4*)&sP[(k0 + kk) * 64 + c];  // broadcast b128
      acc[kk] += p.x * w0 + p.y * w1 + p.z * w2 + p.w * w3;
    }
  }
  // transposed store: d = lane, 4 consecutive k -> one float4
  float* dst = zt + (size_t)b * 262144 + (size_t)lane * 4096 + (size_t)i * 64 + k0;
  *(float4*)dst = make_float4(acc[0], acc[1], acc[2], acc[3]);
  __syncthreads();                        // pe tile dead; alias as elist
  // ---- node MLP row bi: wave w scans edges [w*256, (w+1)*256) ----
  int* elist = (int*)sP;                  // 4096 ints = 16KB
  const int* srcv = eidx;
  const int* dstv = eidx + 4096;
  int cntw = 0;
  unsigned long long ltmask = (lane == 63) ? 0x7fffffffffffffffull
                                           : ((1ull << lane) - 1ull);
#pragma unroll
  for (int q = 0; q < 4; ++q) {
    int e2 = w * 256 + q * 64 + lane;
    bool match = (dstv[e2] == bi);
    unsigned long long mask = __ballot(match);
    if (match) {
      int pos = cntw + __popcll(mask & ltmask);
      elist[w * 256 + pos] = srcv[e2];
    }
    cntw += __popcll(mask);
  }
  float accA = 0.f;
  for (int m = 0; m < cntw; ++m) accA += ne[elist[w * 256 + m] * 64 + lane];
  part[w][lane] = accA;
  __syncthreads();
  if (w == 0) {
    float s = 0.f;
#pragma unroll
    for (int p2 = 0; p2 < 16; ++p2) s += part[p2][lane];
    al[lane] = s;
  } else if (w == 2) {                    // nodeproj a1
    const float* nr = ne + bi * 64;
    float s1 = 0.f;
    for (int d2 = 0; d2 < 64; ++d2) s1 += nr[d2] * Wzz[d2 * 64 + lane];
    a1[bi * 64 + lane] = s1;
  } else if (w == 3) {                    // nodeproj a3
    const float* nr = ne + bi * 64;
    float s3 = 0.f;
    for (int d2 = 0; d2 < 64; ++d2) s3 += nr[d2] * Wzz[(128 + d2) * 64 + lane];
    a3[bi * 64 + lane] = s3;
  }
  __syncthreads();
  // u_node partials: wave w handles d2 in [w*4, w*4+4)
  {
    float s = 0.f;
#pragma unroll
    for (int dd = 0; dd < 4; ++dd) {
      int d2 = w * 4 + dd;
      s += nl[d2] * Wnm[d2 * 64 + lane] + al[d2] * Wnm[(64 + d2) * 64 + lane];
    }
    part[w][lane] = s;
  }
  __syncthreads();
  if (w == 0) {
    float v = bnm[lane];
#pragma unroll
    for (int p2 = 0; p2 < 16; ++p2) v += part[p2][lane];
    v = fmaxf(v, 0.f);
    out0[bi * 64 + lane] = v + nl[lane];
  }
}

// K2: tropical max-plus square per (b,d) slice. grid = 256 (slice)
__global__ __launch_bounds__(1024) void k_tropical(
    const float* __restrict__ zt, float* __restrict__ zt2) {
  int slice = blockIdx.x;                 // b*64 + d
  int t = threadIdx.x, lane = t & 63, w = t >> 6;
  __shared__ float A[4096];               // full 64x64 slice, staged once
  const float* Ag = zt + (size_t)slice * 4096;
  ((float4*)A)[t] = ((const float4*)Ag)[t];
  __syncthreads();
  int i0 = w * 4;                         // wave w owns rows [w*4, w*4+4)
  float acc[4];
#pragma unroll
  for (int ii = 0; ii < 4; ++ii) acc[ii] = A[(i0 + ii) * 64 + lane];  // max(zc,z)
#pragma unroll
  for (int k = 0; k < 64; k += 4) {
    float c0 = A[(k + 0) * 64 + lane], c1 = A[(k + 1) * 64 + lane];
    float c2 = A[(k + 2) * 64 + lane], c3 = A[(k + 3) * 64 + lane];
#pragma unroll
    for (int ii = 0; ii < 4; ++ii) {
      const float4 a = *(const float4*)&A[(i0 + ii) * 64 + k];   // broadcast b128
      float m0 = fmaxf(a.x + c0, a.y + c1);
      float m1 = fmaxf(a.z + c2, a.w + c3);
      acc[ii] = fmaxf(acc[ii], fmaxf(m0, m1));
    }
  }
  float* Og = zt2 + (size_t)slice * 4096 + (size_t)i0 * 64;
#pragma unroll
  for (int ii = 0; ii < 4; ++ii) Og[ii * 64 + lane] = acc[ii];
}

// K3: u_path = relu(a1 + z2@W2 + a3 + bzz) + pe. grid = 256 (bi)
__global__ __launch_bounds__(1024) void k_upath(
    const float* __restrict__ zt2, const float* __restrict__ Wzz,
    const float* __restrict__ bzz, const float* __restrict__ a1,
    const float* __restrict__ a3, const float* __restrict__ pe,
    float* __restrict__ out1) {
  int bi = blockIdx.x;
  int b = bi >> 6, i = bi & 63;
  int t = threadIdx.x, lane = t & 63, w = t >> 6;
  __shared__ float sZ[4096];              // [d][j] 16KB
  __shared__ float sW2[4096];             // W_zz rows 64..127: [d][e] 16KB
  {
    int d2 = t >> 4, jo = (t & 15) * 4;   // gather z2[b][d][i][jo..jo+3]
    const float* src = zt2 + (size_t)b * 262144 + (size_t)d2 * 4096
                     + (size_t)i * 64 + jo;
    *(float4*)&sZ[d2 * 64 + jo] = *(const float4*)src;
  }
  ((float4*)sW2)[t] = ((const float4*)(Wzz + 4096))[t];
  float base = a1[bi * 64 + lane] + bzz[lane];
  __syncthreads();
  int j0 = w * 4;                         // wave w owns 4 consecutive j
  float acc[4] = {base, base, base, base};
#pragma unroll
  for (int d = 0; d < 64; ++d) {
    const float4 z4 = *(const float4*)&sZ[d * 64 + j0];   // broadcast b128
    float wv = sW2[d * 64 + lane];                         // b32, conflict-free
    acc[0] += z4.x * wv;
    acc[1] += z4.y * wv;
    acc[2] += z4.z * wv;
    acc[3] += z4.w * wv;
  }
  const float* a3b = a3 + (size_t)b * 4096;
  size_t ob = (size_t)bi * 4096 + (size_t)j0 * 64;
#pragma unroll
  for (int jj = 0; jj < 4; ++jj) {
    float v = acc[jj] + a3b[(j0 + jj) * 64 + lane];
    v = fmaxf(v, 0.f);
    out1[ob + jj * 64 + lane] = v + pe[ob + jj * 64 + lane];
  }
}

extern "C" void kernel_launch(void* const* d_in, const int* in_sizes, int n_in,
                              void* d_out, int out_size, void* d_ws, size_t ws_size,
                              hipStream_t stream) {
  const float* node = (const float*)d_in[0];
  const float* pe   = (const float*)d_in[1];
  const int*   eidx = (const int*)d_in[2];
  const float* Whz  = (const float*)d_in[3];
  const float* bhz  = (const float*)d_in[4];
  const float* Wzz  = (const float*)d_in[5];
  const float* bzz  = (const float*)d_in[6];
  const float* Wnm  = (const float*)d_in[7];
  const float* bnm  = (const float*)d_in[8];
  float* out0 = (float*)d_out;
  float* out1 = out0 + 16384;
  float* zt  = (float*)d_ws;                // 4 MB
  float* zt2 = zt + 1048576;                // 4 MB
  float* a1  = zt2 + 1048576;               // 64 KB
  float* a3  = a1 + 16384;                  // 64 KB

  hipLaunchKernelGGL(k_pathlin_node, dim3(256), dim3(1024), 0, stream,
                     node, pe, eidx, Whz, bhz, Wzz, Wnm, bnm, zt, a1, a3, out0);
  hipLaunchKernelGGL(k_tropical, dim3(256), dim3(1024), 0, stream, zt, zt2);
  hipLaunchKernelGGL(k_upath, dim3(256), dim3(1024), 0, stream,
                     zt2, Wzz, bzz, a1, a3, pe, out1);
}